// Round 11
// baseline (205.407 us; speedup 1.0000x reference)
//
#include <hip/hip_runtime.h>
#include <hip/hip_bf16.h>

#define L_ 256
#define H_ 4
#define ROWS 2048
#define NEGV (-4294967295.0f)   // -(2^32)+1 as float

typedef unsigned short us16;

__device__ __forceinline__ float us2f(us16 u){ return __uint_as_float(((unsigned)u)<<16); }
__device__ __forceinline__ us16 f2us(float f){ __hip_bfloat16 h=__float2bfloat16(f); return *(us16*)&h; }

// dual bf16 MAC: c += lo(x)*lo(y) + hi(x)*hi(y)
__device__ __forceinline__ float dot2bf(unsigned x, unsigned y, float c){
#if __has_builtin(__builtin_amdgcn_fdot2_f32_bf16)
    typedef __bf16 bf2 __attribute__((ext_vector_type(2)));
    union U{ unsigned u; bf2 v; };
    U ux, uy; ux.u=x; uy.u=y;
    return __builtin_amdgcn_fdot2_f32_bf16(ux.v, uy.v, c, false);
#else
    float r=fmaf(us2f((us16)(x&0xffffu)), us2f((us16)(y&0xffffu)), c);
    return fmaf(us2f((us16)(x>>16)), us2f((us16)(y>>16)), r);
#endif
}

struct KArgs {
    const int *log_seqs, *tmat, *pos_seqs, *neg_seqs;
    const float *item_emb, *posK, *posV, *timeK, *timeV;
    const float *ln1g, *ln1b, *bq, *bk, *bv, *ln2g, *ln2b, *b1, *b2, *lnfg, *lnfb;
    const float *Wq, *Wk, *Wv, *W1, *W2;
    float *qin0, *qin1, *xo0, *xo1, *out;
    unsigned *wsP;              // 7 mats, ROW-pair-major: u32[m*8192 + kp*128 + c] = {W[2kp][c],W[2kp+1][c]}
    us16 *tmK, *tmV, *Qb0, *Kb0, *Vb0, *Qb1, *Kb1, *Vb1;   // Vb* k-pair-major u32-packed
};

// LDS for k_attn (~18.8KB):
//  sS[8][256] f32: raw QK dots; after softmax, first 512B of each row re-used as bf16 A.
//  sPjPr: union { sPj proj table (phase0..softmax) ; sPr AV partials (phase3..LN2) }
struct __align__(16) SmemA {
    float    sS[8*256];      // 8KB
    float    sPjPr[2056];    // 8.2KB union region
    int      sTM[512];       // 2KB
    unsigned sQb[128];       // 512B
    float    sRed[4], sRed2[4];
};

// LayerNorm of 8 LDS rows in place; thread t: row t>>5, 4 elems strided 32.
__device__ __forceinline__ void ln_rows(float* sA,
        const float* __restrict__ g, const float* __restrict__ b,
        float* qin_out, int r0, int tid){
    int r=tid>>5, l=tid&31;
    float* x=sA+r*128;
    float x0=x[l],x1=x[l+32],x2=x[l+64],x3=x[l+96];
    float s=x0+x1+x2+x3;
    #pragma unroll
    for(int o=16;o;o>>=1) s+=__shfl_xor(s,o,64);
    float m=s*(1.f/128.f);
    float d0=x0-m,d1=x1-m,d2=x2-m,d3=x3-m;
    float v=d0*d0+d1*d1+d2*d2+d3*d3;
    #pragma unroll
    for(int o=16;o;o>>=1) v+=__shfl_xor(v,o,64);
    float rstd=rsqrtf(v*(1.f/128.f)+1e-8f);
    float y0=d0*rstd*g[l]+b[l];
    float y1=d1*rstd*g[l+32]+b[l+32];
    float y2=d2*rstd*g[l+64]+b[l+64];
    float y3=d3*rstd*g[l+96]+b[l+96];
    x[l]=y0; x[l+32]=y1; x[l+64]=y2; x[l+96]=y3;
    if(qin_out){
        float* q=qin_out+(size_t)(r0+r)*128;
        q[l]=y0; q[l+32]=y1; q[l+64]=y2; q[l+96]=y3;
    }
}

// k_pre: unchanged (proven).
__global__ __launch_bounds__(256) void k_pre(KArgs a){
    __shared__ __align__(16) float sA[1024];
    int tid=threadIdx.x, bid=blockIdx.x;
    if(bid<768){
        int m=bid>>8, rg=bid&255, r0=rg*8;
        {   // embed 8 rows
            int rl=tid>>5, c4=tid&31;
            int id=a.log_seqs[r0+rl];
            float4 v=((const float4*)a.item_emb)[id*32+c4];
            float sc = id? 11.3137085f : 0.f;   // sqrt(128), pad-zeroed
            v.x*=sc; v.y*=sc; v.z*=sc; v.w*=sc;
            ((float4*)sA)[tid]=v;
        }
        __syncthreads();
        if(m==0){ ln_rows(sA, a.ln1g, a.ln1b, a.qin0, r0, tid); __syncthreads(); }
        const float* Wsrc=(m==0)?a.Wq:(m==1)?a.Wk:a.Wv;
        int cp=tid&63, rp=tid>>6, c0=2*cp, ra=2*rp, rb=ra+1;
        float a00=0,a01=0,a10=0,a11=0;
        const float* Ar=sA+ra*128;
        const float* Br=sA+rb*128;
        #pragma unroll 8
        for(int kk=0;kk<128;kk++){
            float2 wp=((const float2*)(Wsrc+(size_t)kk*128))[cp];
            float x0=Ar[kk], x1=Br[kk];
            a00=fmaf(x0,wp.x,a00); a01=fmaf(x0,wp.y,a01);
            a10=fmaf(x1,wp.x,a10); a11=fmaf(x1,wp.y,a11);
        }
        int r_a=r0+ra, r_b=r0+rb;                 // r_a even, r_b=r_a+1
        if(m==0){
            float b0v=a.bq[c0], b1v=a.bq[c0+1];
            ushort2 s0; s0.x=f2us(a00+b0v); s0.y=f2us(a01+b1v);
            ushort2 s1; s1.x=f2us(a10+b0v); s1.y=f2us(a11+b1v);
            *(ushort2*)(a.Qb0+(size_t)r_a*128+c0)=s0;
            *(ushort2*)(a.Qb0+(size_t)r_b*128+c0)=s1;
        } else if(m==1){
            float b0v=a.bk[c0], b1v=a.bk[c0+1];
            int qa=r_a&255, qb2=r_b&255;
            ushort2 s0; s0.x=f2us(a00+b0v+a.posK[qa*128+c0]);  s0.y=f2us(a01+b1v+a.posK[qa*128+c0+1]);
            ushort2 s1; s1.x=f2us(a10+b0v+a.posK[qb2*128+c0]); s1.y=f2us(a11+b1v+a.posK[qb2*128+c0+1]);
            *(ushort2*)(a.Kb0+(size_t)r_a*128+c0)=s0;
            *(ushort2*)(a.Kb0+(size_t)r_b*128+c0)=s1;
        } else {
            float b0v=a.bv[c0], b1v=a.bv[c0+1];
            int qa=r_a&255, qb2=r_b&255;
            unsigned lo0=f2us(a00+b0v+a.posV[qa*128+c0]);
            unsigned lo1=f2us(a01+b1v+a.posV[qa*128+c0+1]);
            unsigned hi0=f2us(a10+b0v+a.posV[qb2*128+c0]);
            unsigned hi1=f2us(a11+b1v+a.posV[qb2*128+c0+1]);
            unsigned* Vo=(unsigned*)a.Vb0+((size_t)r_a>>1)*128;
            Vo[c0]  =lo0|(hi0<<16);
            Vo[c0+1]=lo1|(hi1<<16);
        }
    } else if(bid<880){
        int j=bid-768; int m=j>>4; int sub=j&15;
        const float* base;
        switch(m){
            case 0: base=a.W1; break;        case 1: base=a.W2; break;
            case 2: base=a.Wq+16384; break;  case 3: base=a.Wk+16384; break;
            case 4: base=a.Wv+16384; break;  case 5: base=a.W1+16384; break;
            default: base=a.W2+16384; break;
        }
        unsigned* dst=a.wsP+(size_t)m*8192;
        #pragma unroll
        for(int t2=0;t2<2;t2++){
            int o=sub*512+t2*256+tid;
            int kp=o>>7, c=o&127;                      // row-pair-major: dst[kp*128+c]
            unsigned lo=f2us(base[(size_t)(2*kp)*128+c]);
            unsigned hi=f2us(base[(size_t)(2*kp+1)*128+c]);
            dst[o]=lo|(hi<<16);
        }
    } else {
        int gi=(bid-880)*256+tid;     // 2 x 8224 float4
        if(gi<8224){
            float4 v=((const float4*)a.timeK)[gi];
            ushort4 o; o.x=f2us(v.x);o.y=f2us(v.y);o.z=f2us(v.z);o.w=f2us(v.w);
            ((ushort4*)a.tmK)[gi]=o;
        } else if(gi<16448){
            int g2=gi-8224;
            float4 v=((const float4*)a.timeV)[g2];
            ushort4 o; o.x=f2us(v.x);o.y=f2us(v.y);o.z=f2us(v.z);o.w=f2us(v.w);
            ((ushort4*)a.tmV)[g2]=o;
        }
    }
}

// k_attn: one block per (b, q-pair {p,255-p}); phases 0-3 + LN2; writes LN2-out (f32) to xo.
__global__ __launch_bounds__(256,7) void k_attn(KArgs a, int layer){
    __shared__ SmemA sm;
    float* sPj=sm.sPjPr;                  // phase0..softmax
    float* sPr=sm.sPjPr;                  // phase3..LN2 (sPj dead by then)
    int tid=threadIdx.x, bid=blockIdx.x;
    int b=bid>>7, p=bid&127;
    int q1=p, q2=255-p, b0=b*L_;
    int r1=b0+q1, r2=b0+q2;
    bool pad1=a.log_seqs[r1]==0, pad2=a.log_seqs[r2]==0;
    const us16* Qb = layer? a.Qb1:a.Qb0;
    const us16* Kb = layer? a.Kb1:a.Kb0;
    const unsigned* Vbu = (const unsigned*)(layer? a.Vb1:a.Vb0);  // pair-major
    const float* qin = layer? a.qin1:a.qin0;
    float* xo = layer? a.xo1 : a.xo0;
    const float scale=0.17677669529663687f;   // 1/sqrt(32)

    if(tid<128){
        int rowq=tid>>6, j=tid&63;
        int r=rowq?r2:r1;
        sm.sQb[rowq*64+j]=((const unsigned*)Qb)[(size_t)r*64+j];   // raw bf16 pairs
    }
    sm.sTM[tid]    =a.tmat[(size_t)r1*L_+tid];
    sm.sTM[256+tid]=a.tmat[(size_t)r2*L_+tid];
    __syncthreads();

    // phase 0: proj table sPj[i2][t][h] = Q[i2]·timeK[t]; coalesced; no barrier after.
    {
        int ch=tid&15, h=ch>>2;
        uint4 qv0=((const uint4*)(sm.sQb))[ch];
        uint4 qv1=((const uint4*)(sm.sQb+64))[ch];
        for(int t=tid>>4; t<257; t+=16){
            uint4 tv=((const uint4*)(a.tmK+(size_t)t*128))[ch];
            float p0=0.f,p1=0.f;
            p0=dot2bf(qv0.x,tv.x,p0); p0=dot2bf(qv0.y,tv.y,p0);
            p0=dot2bf(qv0.z,tv.z,p0); p0=dot2bf(qv0.w,tv.w,p0);
            p1=dot2bf(qv1.x,tv.x,p1); p1=dot2bf(qv1.y,tv.y,p1);
            p1=dot2bf(qv1.z,tv.z,p1); p1=dot2bf(qv1.w,tv.w,p1);
            p0+=__shfl_xor(p0,1,64); p0+=__shfl_xor(p0,2,64);
            p1+=__shfl_xor(p1,1,64); p1+=__shfl_xor(p1,2,64);
            if((ch&3)==0){
                sPj[t*4+h]       =p0;
                sPj[1028+t*4+h]  =p1;   // 1028 = 257*4
            }
        }
    }

    // phase 1 (COALESCED): 16 lanes per K row, 16 rows/pass, 16 passes; raw dots.
    {
        int ch=tid&15, g=tid>>4, h=ch>>2;
        uint4 qv0=((const uint4*)(sm.sQb))[ch];
        uint4 qv1=((const uint4*)(sm.sQb+64))[ch];
        #pragma unroll
        for(int pass=0;pass<16;pass++){
            int k=pass*16+g;
            uint4 kv=((const uint4*)(Kb+(size_t)(b0+k)*128))[ch];
            float p0=0.f,p1=0.f;
            p0=dot2bf(qv0.x,kv.x,p0); p0=dot2bf(qv0.y,kv.y,p0);
            p0=dot2bf(qv0.z,kv.z,p0); p0=dot2bf(qv0.w,kv.w,p0);
            p1=dot2bf(qv1.x,kv.x,p1); p1=dot2bf(qv1.y,kv.y,p1);
            p1=dot2bf(qv1.z,kv.z,p1); p1=dot2bf(qv1.w,kv.w,p1);
            p0+=__shfl_xor(p0,1,64); p0+=__shfl_xor(p0,2,64);
            p1+=__shfl_xor(p1,1,64); p1+=__shfl_xor(p1,2,64);
            if((ch&3)==0){
                sm.sS[h*256+k]    =p0;
                sm.sS[(4+h)*256+k]=p1;
            }
        }
    }
    __syncthreads();

    // phase 2: softmax with fused mask+proj+scale; bf16 A written in place over sS rows.
    {
        int h=tid>>6, lane=tid&63;
        #pragma unroll
        for(int i2=0;i2<2;i2++){
            int qq=i2?q2:q1; bool pad=i2?pad2:pad1;
            float* row=sm.sS+(i2*4+h)*256;
            const int*   tmr=sm.sTM+i2*256;
            const float* pjb=sPj+i2*1028;
            int k0=lane, k1=lane+64, k2=lane+128, k3=lane+192;
            float v0=(k0<=qq&&!pad)? (row[k0]+pjb[tmr[k0]*4+h])*scale : NEGV;
            float v1=(k1<=qq&&!pad)? (row[k1]+pjb[tmr[k1]*4+h])*scale : NEGV;
            float v2=(k2<=qq&&!pad)? (row[k2]+pjb[tmr[k2]*4+h])*scale : NEGV;
            float v3=(k3<=qq&&!pad)? (row[k3]+pjb[tmr[k3]*4+h])*scale : NEGV;
            float mm=fmaxf(fmaxf(v0,v1),fmaxf(v2,v3));
            #pragma unroll
            for(int o=32;o;o>>=1) mm=fmaxf(mm,__shfl_xor(mm,o,64));
            float e0=__expf(v0-mm),e1=__expf(v1-mm),e2=__expf(v2-mm),e3=__expf(v3-mm);
            float ss=e0+e1+e2+e3;
            #pragma unroll
            for(int o=32;o;o>>=1) ss+=__shfl_xor(ss,o,64);
            float inv=1.f/ss;
            us16* ar=(us16*)row;                 // alias: A row over first 512B
            ar[lane]    =f2us(e0*inv); ar[lane+64] =f2us(e1*inv);
            ar[lane+128]=f2us(e2*inv); ar[lane+192]=f2us(e3*inv);
        }
    }
    __syncthreads();

    // phase 3: A @ (V'+timeV[tm]); V pair-major, timeV pairs packed via v_perm.
    {
        int i2=tid>>7, s8=(tid>>4)&7, dq=tid&15;
        int qq=i2?q2:q1; bool pad=i2?pad2:pad1;
        int kend=pad?L_:qq+1;
        int k0=s8*32;
        int kmax=kend-k0; kmax=kmax<0?0:(kmax>32?32:kmax);
        int npair=(kmax+1)>>1;
        const unsigned* arow=(const unsigned*)(sm.sS+(i2*4+(dq>>2))*256);
        const int* tmrow=sm.sTM+i2*256;
        float ac0=0,ac1=0,ac2=0,ac3=0,ac4=0,ac5=0,ac6=0,ac7=0;
        for(int kp=0;kp<npair;kp++){
            int kx=k0+2*kp;
            unsigned aa=arow[kx>>1];
            int tma=tmrow[kx], tmb=tmrow[kx+1];
            const uint4* Vp=(const uint4*)(Vbu+((size_t)(b0+kx)>>1)*128+dq*8);
            uint4 va=Vp[0], vb4=Vp[1];
            uint4 ta=((const uint4*)(a.tmV+(size_t)tma*128))[dq];
            uint4 tb=((const uint4*)(a.tmV+(size_t)tmb*128))[dq];
            ac0=dot2bf(aa,va.x,ac0);  ac1=dot2bf(aa,va.y,ac1);
            ac2=dot2bf(aa,va.z,ac2);  ac3=dot2bf(aa,va.w,ac3);
            ac4=dot2bf(aa,vb4.x,ac4); ac5=dot2bf(aa,vb4.y,ac5);
            ac6=dot2bf(aa,vb4.z,ac6); ac7=dot2bf(aa,vb4.w,ac7);
            unsigned p0=__builtin_amdgcn_perm(tb.x,ta.x,0x05040100u);
            unsigned p1=__builtin_amdgcn_perm(tb.x,ta.x,0x07060302u);
            unsigned p2=__builtin_amdgcn_perm(tb.y,ta.y,0x05040100u);
            unsigned p3=__builtin_amdgcn_perm(tb.y,ta.y,0x07060302u);
            unsigned p4=__builtin_amdgcn_perm(tb.z,ta.z,0x05040100u);
            unsigned p5=__builtin_amdgcn_perm(tb.z,ta.z,0x07060302u);
            unsigned p6=__builtin_amdgcn_perm(tb.w,ta.w,0x05040100u);
            unsigned p7=__builtin_amdgcn_perm(tb.w,ta.w,0x07060302u);
            ac0=dot2bf(aa,p0,ac0); ac1=dot2bf(aa,p1,ac1);
            ac2=dot2bf(aa,p2,ac2); ac3=dot2bf(aa,p3,ac3);
            ac4=dot2bf(aa,p4,ac4); ac5=dot2bf(aa,p5,ac5);
            ac6=dot2bf(aa,p6,ac6); ac7=dot2bf(aa,p7,ac7);
        }
        float* dst=sPr+(i2*8+s8)*128+dq*8;
        ((float4*)dst)[0]=make_float4(ac0,ac1,ac2,ac3);
        ((float4*)dst)[1]=make_float4(ac4,ac5,ac6,ac7);
    }
    __syncthreads();

    // epilogue: +qin residual, LN2 (single barrier) -> xo (f32, global)
    int ii=tid>>7, l=tid&127;
    int rr = ii? r2:r1;
    {
        float v=qin[(size_t)rr*128+l];
        #pragma unroll
        for(int sl=0;sl<8;sl++) v+=sPr[(ii*8+sl)*128+l];
        float s=v, s2=v*v;
        #pragma unroll
        for(int o=32;o;o>>=1){ s+=__shfl_xor(s,o,64); s2+=__shfl_xor(s2,o,64); }
        if((tid&63)==0){ sm.sRed[ii*2+((tid>>6)&1)]=s; sm.sRed2[ii*2+((tid>>6)&1)]=s2; }
        __syncthreads();
        float m =(sm.sRed[ii*2] +sm.sRed[ii*2+1]) *(1.f/128.f);
        float ms=(sm.sRed2[ii*2]+sm.sRed2[ii*2+1])*(1.f/128.f);
        float rstd=rsqrtf(fmaxf(ms-m*m,0.f)+1e-8f);
        float y=(v-m)*rstd*a.ln2g[layer*128+l]+a.ln2b[layer*128+l];
        xo[(size_t)rr*128+l]=y;
    }
}

// k_tail: 512 blocks x 4 rows; thread (ii=tid>>7, c=tid&127) owns rows base+ii and
// base+2+ii -> every weight load feeds 2 rows. FFN -> (L0) LN1'+QKV(L1) | (L1) LNf+logits.
__global__ __launch_bounds__(256,8) void k_tail(KArgs a, int layer){
    __shared__ __align__(16) float    xf[4*128];   // 2KB  LN2-out (f32)
    __shared__ __align__(16) unsigned xb[4*64];    // 1KB  bf16 pairs (gemv input)
    __shared__ __align__(16) unsigned hb[4*64];    // 1KB  relu h
    __shared__ __align__(16) unsigned yb[4*64];    // 1KB  raw f (L0 K/V input)
    __shared__ float sR[16];
    int tid=threadIdx.x, bid=blockIdx.x;
    int c=tid&127, ii=tid>>7, wh=(tid>>6)&1;
    int base=bid*4;
    int ra=base+ii, rb=base+2+ii;
    bool padA=a.log_seqs[ra]==0, padB=a.log_seqs[rb]==0;
    const float* xo = layer? a.xo1 : a.xo0;
    for(int j=tid;j<512;j+=256){
        float v=xo[(size_t)base*128+j];
        xf[j]=v;
        ((us16*)xb)[j]=f2us(v);
    }
    __syncthreads();

    // FFN1: h = relu(x@W1+b1)
    {
        const unsigned* wp=a.wsP+(size_t)(layer?5:0)*8192;
        float s0=0.f,s1=0.f;
        #pragma unroll 8
        for(int kp=0;kp<64;kp++){
            unsigned w=wp[kp*128+c];
            s0=dot2bf(xb[ii*64+kp],     w, s0);
            s1=dot2bf(xb[(ii+2)*64+kp], w, s1);
        }
        float b1v=a.b1[layer*128+c];
        ((us16*)hb)[ii*128+c]    =f2us(fmaxf(s0+b1v,0.f));
        ((us16*)hb)[(ii+2)*128+c]=f2us(fmaxf(s1+b1v,0.f));
    }
    __syncthreads();

    // FFN2: f = h@W2+b2 + x ; mask
    float f0,f1;
    {
        const unsigned* wp=a.wsP+(size_t)(layer?6:1)*8192;
        float s0=0.f,s1=0.f;
        #pragma unroll 8
        for(int kp=0;kp<64;kp++){
            unsigned w=wp[kp*128+c];
            s0=dot2bf(hb[ii*64+kp],     w, s0);
            s1=dot2bf(hb[(ii+2)*64+kp], w, s1);
        }
        float b2v=a.b2[layer*128+c];
        f0=s0+b2v+xf[ii*128+c];     if(padA) f0=0.f;
        f1=s1+b2v+xf[(ii+2)*128+c]; if(padB) f1=0.f;
    }

    if(layer==0){
        // LN1' per row (single barrier via E[x^2]); raw f -> yb
        ((us16*)yb)[ii*128+c]    =f2us(f0);
        ((us16*)yb)[(ii+2)*128+c]=f2us(f1);
        float s0=f0,q0=f0*f0,s1=f1,q1=f1*f1;
        #pragma unroll
        for(int o=32;o;o>>=1){
            s0+=__shfl_xor(s0,o,64); q0+=__shfl_xor(q0,o,64);
            s1+=__shfl_xor(s1,o,64); q1+=__shfl_xor(q1,o,64);
        }
        if((tid&63)==0){
            sR[ii*8+wh*4+0]=s0; sR[ii*8+wh*4+1]=q0;
            sR[ii*8+wh*4+2]=s1; sR[ii*8+wh*4+3]=q1;
        }
        __syncthreads();
        float m0=(sR[ii*8+0]+sR[ii*8+4])*(1.f/128.f);
        float e0=(sR[ii*8+1]+sR[ii*8+5])*(1.f/128.f);
        float m1=(sR[ii*8+2]+sR[ii*8+6])*(1.f/128.f);
        float e1=(sR[ii*8+3]+sR[ii*8+7])*(1.f/128.f);
        float r0=rsqrtf(fmaxf(e0-m0*m0,0.f)+1e-8f);
        float r1=rsqrtf(fmaxf(e1-m1*m1,0.f)+1e-8f);
        float g=a.ln1g[128+c], bb=a.ln1b[128+c];
        float y0=(f0-m0)*r0*g+bb;
        float y1=(f1-m1)*r1*g+bb;
        a.qin1[(size_t)ra*128+c]=y0;
        a.qin1[(size_t)rb*128+c]=y1;
        ((us16*)xb)[ii*128+c]    =f2us(y0);
        ((us16*)xb)[(ii+2)*128+c]=f2us(y1);
        __syncthreads();
        // Q / K / V (layer1) gemvs; read-only LDS -> no barriers between
        {
            const unsigned* wp=a.wsP+(size_t)2*8192;
            float s0g=0.f,s1g=0.f;
            #pragma unroll 8
            for(int kp=0;kp<64;kp++){
                unsigned w=wp[kp*128+c];
                s0g=dot2bf(xb[ii*64+kp],     w, s0g);
                s1g=dot2bf(xb[(ii+2)*64+kp], w, s1g);
            }
            float bqv=a.bq[128+c];
            a.Qb1[(size_t)ra*128+c]=f2us(s0g+bqv);
            a.Qb1[(size_t)rb*128+c]=f2us(s1g+bqv);
        }
        {
            const unsigned* wp=a.wsP+(size_t)3*8192;
            float s0g=0.f,s1g=0.f;
            #pragma unroll 8
            for(int kp=0;kp<64;kp++){
                unsigned w=wp[kp*128+c];
                s0g=dot2bf(yb[ii*64+kp],     w, s0g);
                s1g=dot2bf(yb[(ii+2)*64+kp], w, s1g);
            }
            float bkv=a.bk[128+c];
            a.Kb1[(size_t)ra*128+c]=f2us(s0g+bkv+a.posK[(ra&255)*128+c]);
            a.Kb1[(size_t)rb*128+c]=f2us(s1g+bkv+a.posK[(rb&255)*128+c]);
        }
        {
            const unsigned* wp=a.wsP+(size_t)4*8192;
            float s0g=0.f,s1g=0.f;
            #pragma unroll 8
            for(int kp=0;kp<64;kp++){
                unsigned w=wp[kp*128+c];
                s0g=dot2bf(yb[ii*64+kp],     w, s0g);
                s1g=dot2bf(yb[(ii+2)*64+kp], w, s1g);
            }
            float bvv=a.bv[128+c];
            float v0=s0g+bvv+a.posV[(ra&255)*128+c];
            float v1=s1g+bvv+a.posV[(rb&255)*128+c];
            ((us16*)a.Vb1)[((size_t)ra>>1)*256+2*c+(ra&1)]=f2us(v0);   // pair-major
            ((us16*)a.Vb1)[((size_t)rb>>1)*256+2*c+(rb&1)]=f2us(v1);
        }
    } else {
        // LNf per row (single barrier) -> xf ; logits
        float s0=f0,q0=f0*f0,s1=f1,q1=f1*f1;
        #pragma unroll
        for(int o=32;o;o>>=1){
            s0+=__shfl_xor(s0,o,64); q0+=__shfl_xor(q0,o,64);
            s1+=__shfl_xor(s1,o,64); q1+=__shfl_xor(q1,o,64);
        }
        if((tid&63)==0){
            sR[ii*8+wh*4+0]=s0; sR[ii*8+wh*4+1]=q0;
            sR[ii*8+wh*4+2]=s1; sR[ii*8+wh*4+3]=q1;
        }
        __syncthreads();
        float m0=(sR[ii*8+0]+sR[ii*8+4])*(1.f/128.f);
        float e0=(sR[ii*8+1]+sR[ii*8+5])*(1.f/128.f);
        float m1=(sR[ii*8+2]+sR[ii*8+6])*(1.f/128.f);
        float e1=(sR[ii*8+3]+sR[ii*8+7])*(1.f/128.f);
        float r0=rsqrtf(fmaxf(e0-m0*m0,0.f)+1e-8f);
        float r1=rsqrtf(fmaxf(e1-m1*m1,0.f)+1e-8f);
        float g=a.lnfg[c], bb=a.lnfb[c];
        xf[ii*128+c]    =(f0-m0)*r0*g+bb;
        xf[(ii+2)*128+c]=(f1-m1)*r1*g+bb;
        __syncthreads();
        int w=tid>>6, lane=tid&63;
        int r=base+w;                       // xf[w] holds row base+w (see layout)
        #pragma unroll
        for(int neg=0;neg<2;neg++){
            int id = neg? a.neg_seqs[r] : a.pos_seqs[r];
            const float* e=a.item_emb+(size_t)id*128;
            float s=xf[w*128+lane]*e[lane]+xf[w*128+lane+64]*e[lane+64];
            #pragma unroll
            for(int o=32;o;o>>=1) s+=__shfl_xor(s,o,64);
            if(lane==0) a.out[neg*ROWS+r]=s;
        }
    }
}

extern "C" void kernel_launch(void* const* d_in, const int* in_sizes, int n_in,
                              void* d_out, int out_size, void* d_ws, size_t ws_size,
                              hipStream_t stream) {
    KArgs a;
    a.log_seqs=(const int*)d_in[1];
    a.tmat    =(const int*)d_in[2];
    a.pos_seqs=(const int*)d_in[3];
    a.neg_seqs=(const int*)d_in[4];
    a.item_emb=(const float*)d_in[5];
    a.posK =(const float*)d_in[6];
    a.posV =(const float*)d_in[7];
    a.timeK=(const float*)d_in[8];
    a.timeV=(const float*)d_in[9];
    a.ln1g=(const float*)d_in[10];
    a.ln1b=(const float*)d_in[11];
    a.Wq=(const float*)d_in[12];
    a.bq=(const float*)d_in[13];
    a.Wk=(const float*)d_in[14];
    a.bk=(const float*)d_in[15];
    a.Wv=(const float*)d_in[16];
    a.bv=(const float*)d_in[17];
    a.ln2g=(const float*)d_in[18];
    a.ln2b=(const float*)d_in[19];
    a.W1=(const float*)d_in[20];
    a.b1=(const float*)d_in[21];
    a.W2=(const float*)d_in[22];
    a.b2=(const float*)d_in[23];
    a.lnfg=(const float*)d_in[24];
    a.lnfb=(const float*)d_in[25];

    const size_t MB=1u<<20;
    char* w=(char*)d_ws;
    a.qin0=(float*)(w+0*MB);
    a.qin1=(float*)(w+1*MB);
    a.Qb0 =(us16*) (w+2*MB);
    a.Kb0 =(us16*) (w+2*MB+512*1024);
    a.Vb0 =(us16*) (w+3*MB);
    a.Qb1 =(us16*) (w+3*MB+512*1024);
    a.Kb1 =(us16*) (w+4*MB);
    a.Vb1 =(us16*) (w+4*MB+512*1024);
    a.wsP =(unsigned*)(w+5*MB);           // 7 x 32KB row-pair-major bf16
    a.tmK =(us16*) (w+5*MB+256*1024);
    a.tmV =(us16*) (w+5*MB+384*1024);
    a.xo0 =(float*)(w+6*MB);
    a.xo1 =(float*)(w+7*MB);
    a.out =(float*)d_out;

    k_pre <<<946,256,0,stream>>>(a);
    k_attn<<<1024,256,0,stream>>>(a,0);
    k_tail<<<512,256,0,stream>>>(a,0);
    k_attn<<<1024,256,0,stream>>>(a,1);
    k_tail<<<512,256,0,stream>>>(a,1);
}

// Round 12
// 191.532 us; speedup vs baseline: 1.0724x; 1.0724x over previous
//
#include <hip/hip_runtime.h>
#include <hip/hip_bf16.h>

#define L_ 256
#define H_ 4
#define ROWS 2048
#define NEGV (-4294967295.0f)   // -(2^32)+1 as float

typedef unsigned short us16;

__device__ __forceinline__ float us2f(us16 u){ return __uint_as_float(((unsigned)u)<<16); }
__device__ __forceinline__ us16 f2us(float f){ __hip_bfloat16 h=__float2bfloat16(f); return *(us16*)&h; }

// dual bf16 MAC: c += lo(x)*lo(y) + hi(x)*hi(y)
__device__ __forceinline__ float dot2bf(unsigned x, unsigned y, float c){
#if __has_builtin(__builtin_amdgcn_fdot2_f32_bf16)
    typedef __bf16 bf2 __attribute__((ext_vector_type(2)));
    union U{ unsigned u; bf2 v; };
    U ux, uy; ux.u=x; uy.u=y;
    return __builtin_amdgcn_fdot2_f32_bf16(ux.v, uy.v, c, false);
#else
    float r=fmaf(us2f((us16)(x&0xffffu)), us2f((us16)(y&0xffffu)), c);
    return fmaf(us2f((us16)(x>>16)), us2f((us16)(y>>16)), r);
#endif
}

struct KArgs {
    const int *log_seqs, *tmat, *pos_seqs, *neg_seqs;
    const float *item_emb, *posK, *posV, *timeK, *timeV;
    const float *ln1g, *ln1b, *bq, *bk, *bv, *ln2g, *ln2b, *b1, *b2, *lnfg, *lnfb;
    const float *Wq, *Wk, *Wv, *W1, *W2;
    float *qin0, *qin1, *out;
    unsigned *wsP;              // 7 mats, ROW-pair-major: u32[m*8192 + kp*128 + c] = {W[2kp][c],W[2kp+1][c]}
    us16 *tmK, *tmV, *Qb0, *Kb0, *Vb0, *Qb1, *Kb1, *Vb1;   // Vb* k-pair-major u32-packed
};

// LDS (~23KB):
//  sS[8][256] f32: raw QK dots; after softmax, FIRST 512B of each row re-used as bf16 A.
//  sPjPr: union { sPj proj table STRIDE-5 padded (phase0..softmax): [i2][257][5] ->
//                 bank=(5t+h)%32 hits all 32 banks (5 coprime 32), vs stride-4's 8-way
//                 conflict ; sPr[16][128] AV partials (phase3..LN2) }
struct __align__(16) Smem {
    float    sS[8*256];      // 8KB
    float    sPjPr[2570];    // 10.3KB union region (max(2*257*5, 16*128))
    int      sTM[512];       // 2KB
    unsigned sQb[128];       // 512B
    float    sX[256];        // 1KB
    unsigned sXb[128];
    unsigned sHb[128];
    unsigned sYb[128];
    float    sRed[4], sRed2[4], sRB[8];
};

// row-pair-major GEMV (coalesced): out_c = sum_k x[k]*W[k][c]
__device__ __forceinline__ float gemv128(const unsigned* __restrict__ wp,
                                         const unsigned* __restrict__ xp, int c){
    float s0=0.f, s1=0.f;
    #pragma unroll 8
    for(int kp=0;kp<64;kp+=2){
        s0=dot2bf(xp[kp],   wp[kp*128+c],     s0);
        s1=dot2bf(xp[kp+1], wp[(kp+1)*128+c], s1);
    }
    return s0+s1;
}

// LayerNorm of 8 LDS rows in place; thread t: row t>>5, 4 elems strided 32.
__device__ __forceinline__ void ln_rows(float* sA,
        const float* __restrict__ g, const float* __restrict__ b,
        float* qin_out, int r0, int tid){
    int r=tid>>5, l=tid&31;
    float* x=sA+r*128;
    float x0=x[l],x1=x[l+32],x2=x[l+64],x3=x[l+96];
    float s=x0+x1+x2+x3;
    #pragma unroll
    for(int o=16;o;o>>=1) s+=__shfl_xor(s,o,64);
    float m=s*(1.f/128.f);
    float d0=x0-m,d1=x1-m,d2=x2-m,d3=x3-m;
    float v=d0*d0+d1*d1+d2*d2+d3*d3;
    #pragma unroll
    for(int o=16;o;o>>=1) v+=__shfl_xor(v,o,64);
    float rstd=rsqrtf(v*(1.f/128.f)+1e-8f);
    float y0=d0*rstd*g[l]+b[l];
    float y1=d1*rstd*g[l+32]+b[l+32];
    float y2=d2*rstd*g[l+64]+b[l+64];
    float y3=d3*rstd*g[l+96]+b[l+96];
    x[l]=y0; x[l+32]=y1; x[l+64]=y2; x[l+96]=y3;
    if(qin_out){
        float* q=qin_out+(size_t)(r0+r)*128;
        q[l]=y0; q[l+32]=y1; q[l+64]=y2; q[l+96]=y3;
    }
}

// k_pre: unchanged (proven).
__global__ __launch_bounds__(256) void k_pre(KArgs a){
    __shared__ __align__(16) float sA[1024];
    int tid=threadIdx.x, bid=blockIdx.x;
    if(bid<768){
        int m=bid>>8, rg=bid&255, r0=rg*8;
        {   // embed 8 rows
            int rl=tid>>5, c4=tid&31;
            int id=a.log_seqs[r0+rl];
            float4 v=((const float4*)a.item_emb)[id*32+c4];
            float sc = id? 11.3137085f : 0.f;   // sqrt(128), pad-zeroed
            v.x*=sc; v.y*=sc; v.z*=sc; v.w*=sc;
            ((float4*)sA)[tid]=v;
        }
        __syncthreads();
        if(m==0){ ln_rows(sA, a.ln1g, a.ln1b, a.qin0, r0, tid); __syncthreads(); }
        const float* Wsrc=(m==0)?a.Wq:(m==1)?a.Wk:a.Wv;
        int cp=tid&63, rp=tid>>6, c0=2*cp, ra=2*rp, rb=ra+1;
        float a00=0,a01=0,a10=0,a11=0;
        const float* Ar=sA+ra*128;
        const float* Br=sA+rb*128;
        #pragma unroll 8
        for(int kk=0;kk<128;kk++){
            float2 wp=((const float2*)(Wsrc+(size_t)kk*128))[cp];
            float x0=Ar[kk], x1=Br[kk];
            a00=fmaf(x0,wp.x,a00); a01=fmaf(x0,wp.y,a01);
            a10=fmaf(x1,wp.x,a10); a11=fmaf(x1,wp.y,a11);
        }
        int r_a=r0+ra, r_b=r0+rb;                 // r_a even, r_b=r_a+1
        if(m==0){
            float b0v=a.bq[c0], b1v=a.bq[c0+1];
            ushort2 s0; s0.x=f2us(a00+b0v); s0.y=f2us(a01+b1v);
            ushort2 s1; s1.x=f2us(a10+b0v); s1.y=f2us(a11+b1v);
            *(ushort2*)(a.Qb0+(size_t)r_a*128+c0)=s0;
            *(ushort2*)(a.Qb0+(size_t)r_b*128+c0)=s1;
        } else if(m==1){
            float b0v=a.bk[c0], b1v=a.bk[c0+1];
            int qa=r_a&255, qb2=r_b&255;
            ushort2 s0; s0.x=f2us(a00+b0v+a.posK[qa*128+c0]);  s0.y=f2us(a01+b1v+a.posK[qa*128+c0+1]);
            ushort2 s1; s1.x=f2us(a10+b0v+a.posK[qb2*128+c0]); s1.y=f2us(a11+b1v+a.posK[qb2*128+c0+1]);
            *(ushort2*)(a.Kb0+(size_t)r_a*128+c0)=s0;
            *(ushort2*)(a.Kb0+(size_t)r_b*128+c0)=s1;
        } else {
            float b0v=a.bv[c0], b1v=a.bv[c0+1];
            int qa=r_a&255, qb2=r_b&255;
            unsigned lo0=f2us(a00+b0v+a.posV[qa*128+c0]);
            unsigned lo1=f2us(a01+b1v+a.posV[qa*128+c0+1]);
            unsigned hi0=f2us(a10+b0v+a.posV[qb2*128+c0]);
            unsigned hi1=f2us(a11+b1v+a.posV[qb2*128+c0+1]);
            unsigned* Vo=(unsigned*)a.Vb0+((size_t)r_a>>1)*128;
            Vo[c0]  =lo0|(hi0<<16);
            Vo[c0+1]=lo1|(hi1<<16);
        }
    } else if(bid<880){
        int j=bid-768; int m=j>>4; int sub=j&15;
        const float* base;
        switch(m){
            case 0: base=a.W1; break;        case 1: base=a.W2; break;
            case 2: base=a.Wq+16384; break;  case 3: base=a.Wk+16384; break;
            case 4: base=a.Wv+16384; break;  case 5: base=a.W1+16384; break;
            default: base=a.W2+16384; break;
        }
        unsigned* dst=a.wsP+(size_t)m*8192;
        #pragma unroll
        for(int t2=0;t2<2;t2++){
            int o=sub*512+t2*256+tid;
            int kp=o>>7, c=o&127;                      // row-pair-major: dst[kp*128+c]
            unsigned lo=f2us(base[(size_t)(2*kp)*128+c]);
            unsigned hi=f2us(base[(size_t)(2*kp+1)*128+c]);
            dst[o]=lo|(hi<<16);
        }
    } else {
        int gi=(bid-880)*256+tid;     // 2 x 8224 float4
        if(gi<8224){
            float4 v=((const float4*)a.timeK)[gi];
            ushort4 o; o.x=f2us(v.x);o.y=f2us(v.y);o.z=f2us(v.z);o.w=f2us(v.w);
            ((ushort4*)a.tmK)[gi]=o;
        } else if(gi<16448){
            int g2=gi-8224;
            float4 v=((const float4*)a.timeV)[g2];
            ushort4 o; o.x=f2us(v.x);o.y=f2us(v.y);o.z=f2us(v.z);o.w=f2us(v.w);
            ((ushort4*)a.tmV)[g2]=o;
        }
    }
}

// one block per (b, q-pair {p,255-p}); round-10 structure + stride-5 proj table.
__global__ __launch_bounds__(256,7) void k_blk(KArgs a, int layer){
    __shared__ Smem sm;
    float* sPj=sm.sPjPr;                  // phase0..softmax (stride-5 rows)
    float* sPr=sm.sPjPr;                  // phase3..LN2 (sPj dead by then)
    int tid=threadIdx.x, bid=blockIdx.x;
    int b=bid>>7, p=bid&127;
    int q1=p, q2=255-p, b0=b*L_;
    int r1=b0+q1, r2=b0+q2;
    bool pad1=a.log_seqs[r1]==0, pad2=a.log_seqs[r2]==0;
    const us16* Qb = layer? a.Qb1:a.Qb0;
    const us16* Kb = layer? a.Kb1:a.Kb0;
    const unsigned* Vbu = (const unsigned*)(layer? a.Vb1:a.Vb0);  // pair-major
    const float* qin = layer? a.qin1:a.qin0;
    const float scale=0.17677669529663687f;   // 1/sqrt(32)

    if(tid<128){
        int rowq=tid>>6, j=tid&63;
        int r=rowq?r2:r1;
        sm.sQb[rowq*64+j]=((const unsigned*)Qb)[(size_t)r*64+j];   // raw bf16 pairs
    }
    sm.sTM[tid]    =a.tmat[(size_t)r1*L_+tid];
    sm.sTM[256+tid]=a.tmat[(size_t)r2*L_+tid];
    __syncthreads();

    // phase 0: proj table sPj[i2][t*5+h] = Q[i2]·timeK[t]; 16 lanes/row coalesced,
    // 4-lane shfl reduce per head.  No barrier after (phase 1 writes disjoint sS).
    {
        int ch=tid&15, h=ch>>2;
        uint4 qv0=((const uint4*)(sm.sQb))[ch];
        uint4 qv1=((const uint4*)(sm.sQb+64))[ch];
        for(int t=tid>>4; t<257; t+=16){
            uint4 tv=((const uint4*)(a.tmK+(size_t)t*128))[ch];
            float p0=0.f,p1=0.f;
            p0=dot2bf(qv0.x,tv.x,p0); p0=dot2bf(qv0.y,tv.y,p0);
            p0=dot2bf(qv0.z,tv.z,p0); p0=dot2bf(qv0.w,tv.w,p0);
            p1=dot2bf(qv1.x,tv.x,p1); p1=dot2bf(qv1.y,tv.y,p1);
            p1=dot2bf(qv1.z,tv.z,p1); p1=dot2bf(qv1.w,tv.w,p1);
            p0+=__shfl_xor(p0,1,64); p0+=__shfl_xor(p0,2,64);
            p1+=__shfl_xor(p1,1,64); p1+=__shfl_xor(p1,2,64);
            if((ch&3)==0){
                sPj[t*5+h]       =p0;
                sPj[1285+t*5+h]  =p1;   // 1285 = 257*5
            }
        }
    }

    // phase 1 (COALESCED): 16 lanes per K row, 16 rows/pass, 16 passes; raw dots.
    {
        int ch=tid&15, g=tid>>4, h=ch>>2;
        uint4 qv0=((const uint4*)(sm.sQb))[ch];
        uint4 qv1=((const uint4*)(sm.sQb+64))[ch];
        #pragma unroll
        for(int pass=0;pass<16;pass++){
            int k=pass*16+g;
            uint4 kv=((const uint4*)(Kb+(size_t)(b0+k)*128))[ch];
            float p0=0.f,p1=0.f;
            p0=dot2bf(qv0.x,kv.x,p0); p0=dot2bf(qv0.y,kv.y,p0);
            p0=dot2bf(qv0.z,kv.z,p0); p0=dot2bf(qv0.w,kv.w,p0);
            p1=dot2bf(qv1.x,kv.x,p1); p1=dot2bf(qv1.y,kv.y,p1);
            p1=dot2bf(qv1.z,kv.z,p1); p1=dot2bf(qv1.w,kv.w,p1);
            p0+=__shfl_xor(p0,1,64); p0+=__shfl_xor(p0,2,64);
            p1+=__shfl_xor(p1,1,64); p1+=__shfl_xor(p1,2,64);
            if((ch&3)==0){
                sm.sS[h*256+k]    =p0;
                sm.sS[(4+h)*256+k]=p1;
            }
        }
    }
    __syncthreads();

    // phase 2: softmax with fused mask+proj+scale; bf16 A written in place over sS rows.
    {
        int h=tid>>6, lane=tid&63;
        #pragma unroll
        for(int i2=0;i2<2;i2++){
            int qq=i2?q2:q1; bool pad=i2?pad2:pad1;
            float* row=sm.sS+(i2*4+h)*256;
            const int*   tmr=sm.sTM+i2*256;
            const float* pjb=sPj+i2*1285;
            int k0=lane, k1=lane+64, k2=lane+128, k3=lane+192;
            float v0=(k0<=qq&&!pad)? (row[k0]+pjb[tmr[k0]*5+h])*scale : NEGV;
            float v1=(k1<=qq&&!pad)? (row[k1]+pjb[tmr[k1]*5+h])*scale : NEGV;
            float v2=(k2<=qq&&!pad)? (row[k2]+pjb[tmr[k2]*5+h])*scale : NEGV;
            float v3=(k3<=qq&&!pad)? (row[k3]+pjb[tmr[k3]*5+h])*scale : NEGV;
            float mm=fmaxf(fmaxf(v0,v1),fmaxf(v2,v3));
            #pragma unroll
            for(int o=32;o;o>>=1) mm=fmaxf(mm,__shfl_xor(mm,o,64));
            float e0=__expf(v0-mm),e1=__expf(v1-mm),e2=__expf(v2-mm),e3=__expf(v3-mm);
            float ss=e0+e1+e2+e3;
            #pragma unroll
            for(int o=32;o;o>>=1) ss+=__shfl_xor(ss,o,64);
            float inv=1.f/ss;
            us16* ar=(us16*)row;                 // alias: A row over first 512B
            ar[lane]    =f2us(e0*inv); ar[lane+64] =f2us(e1*inv);
            ar[lane+128]=f2us(e2*inv); ar[lane+192]=f2us(e3*inv);
        }
    }
    __syncthreads();

    // phase 3: A @ (V'+timeV[tm]); V pair-major, timeV pairs packed via v_perm.
    // sPr overlays sPj (dead).  A read from sS-row alias.
    {
        int i2=tid>>7, s8=(tid>>4)&7, dq=tid&15;
        int qq=i2?q2:q1; bool pad=i2?pad2:pad1;
        int kend=pad?L_:qq+1;
        int k0=s8*32;
        int kmax=kend-k0; kmax=kmax<0?0:(kmax>32?32:kmax);
        int npair=(kmax+1)>>1;
        const unsigned* arow=(const unsigned*)(sm.sS+(i2*4+(dq>>2))*256);
        const int* tmrow=sm.sTM+i2*256;
        float ac0=0,ac1=0,ac2=0,ac3=0,ac4=0,ac5=0,ac6=0,ac7=0;
        for(int kp=0;kp<npair;kp++){
            int kx=k0+2*kp;
            unsigned aa=arow[kx>>1];
            int tma=tmrow[kx], tmb=tmrow[kx+1];
            const uint4* Vp=(const uint4*)(Vbu+((size_t)(b0+kx)>>1)*128+dq*8);
            uint4 va=Vp[0], vb4=Vp[1];
            uint4 ta=((const uint4*)(a.tmV+(size_t)tma*128))[dq];
            uint4 tb=((const uint4*)(a.tmV+(size_t)tmb*128))[dq];
            ac0=dot2bf(aa,va.x,ac0);  ac1=dot2bf(aa,va.y,ac1);
            ac2=dot2bf(aa,va.z,ac2);  ac3=dot2bf(aa,va.w,ac3);
            ac4=dot2bf(aa,vb4.x,ac4); ac5=dot2bf(aa,vb4.y,ac5);
            ac6=dot2bf(aa,vb4.z,ac6); ac7=dot2bf(aa,vb4.w,ac7);
            unsigned p0=__builtin_amdgcn_perm(tb.x,ta.x,0x05040100u);
            unsigned p1=__builtin_amdgcn_perm(tb.x,ta.x,0x07060302u);
            unsigned p2=__builtin_amdgcn_perm(tb.y,ta.y,0x05040100u);
            unsigned p3=__builtin_amdgcn_perm(tb.y,ta.y,0x07060302u);
            unsigned p4=__builtin_amdgcn_perm(tb.z,ta.z,0x05040100u);
            unsigned p5=__builtin_amdgcn_perm(tb.z,ta.z,0x07060302u);
            unsigned p6=__builtin_amdgcn_perm(tb.w,ta.w,0x05040100u);
            unsigned p7=__builtin_amdgcn_perm(tb.w,ta.w,0x07060302u);
            ac0=dot2bf(aa,p0,ac0); ac1=dot2bf(aa,p1,ac1);
            ac2=dot2bf(aa,p2,ac2); ac3=dot2bf(aa,p3,ac3);
            ac4=dot2bf(aa,p4,ac4); ac5=dot2bf(aa,p5,ac5);
            ac6=dot2bf(aa,p6,ac6); ac7=dot2bf(aa,p7,ac7);
        }
        float* dst=sPr+(i2*8+s8)*128+dq*8;
        ((float4*)dst)[0]=make_float4(ac0,ac1,ac2,ac3);
        ((float4*)dst)[1]=make_float4(ac4,ac5,ac6,ac7);
    }
    __syncthreads();

    // epilogue: +qin residual, LN2 (single barrier: Var = E[x^2]-m^2) -> sX/sXb
    int ii=tid>>7, l=tid&127;
    bool padown = ii? pad2:pad1;
    int rr = ii? r2:r1;
    int qown = ii? q2:q1;
    {
        float v=qin[(size_t)rr*128+l];
        #pragma unroll
        for(int sl=0;sl<8;sl++) v+=sPr[(ii*8+sl)*128+l];
        float s=v, s2=v*v;
        #pragma unroll
        for(int o=32;o;o>>=1){ s+=__shfl_xor(s,o,64); s2+=__shfl_xor(s2,o,64); }
        if((tid&63)==0){ sm.sRed[ii*2+((tid>>6)&1)]=s; sm.sRed2[ii*2+((tid>>6)&1)]=s2; }
        __syncthreads();
        float m =(sm.sRed[ii*2] +sm.sRed[ii*2+1]) *(1.f/128.f);
        float ms=(sm.sRed2[ii*2]+sm.sRed2[ii*2+1])*(1.f/128.f);
        float rstd=rsqrtf(fmaxf(ms-m*m,0.f)+1e-8f);
        float y=(v-m)*rstd*a.ln2g[layer*128+l]+a.ln2b[layer*128+l];
        sm.sX[ii*128+l]=y;
        ((us16*)sm.sXb)[ii*128+l]=f2us(y);
    }
    __syncthreads();

    // FFN: h = relu(X@W1+b1); f = h@W2+b2 + X; mask.
    int cc=l;
    {
        float h1=gemv128(a.wsP+(size_t)(layer?5:0)*8192, sm.sXb+ii*64, cc);
        h1=fmaxf(h1+a.b1[layer*128+cc],0.f);
        ((us16*)sm.sHb)[ii*128+cc]=f2us(h1);
    }
    __syncthreads();
    float f;
    {
        f=gemv128(a.wsP+(size_t)(layer?6:1)*8192, sm.sHb+ii*64, cc)
          +a.b2[layer*128+cc]+sm.sX[ii*128+cc];
        if(padown) f=0.f;
    }

    if(layer==0){
        // LN1(layer1) on f (single barrier); raw f -> sYb
        ((us16*)sm.sYb)[ii*128+cc]=f2us(f);
        float s=f, s2=f*f;
        #pragma unroll
        for(int o=32;o;o>>=1){ s+=__shfl_xor(s,o,64); s2+=__shfl_xor(s2,o,64); }
        if((tid&63)==0){ sm.sRB[ii*2+((tid>>6)&1)]=s; sm.sRB[4+ii*2+((tid>>6)&1)]=s2; }
        __syncthreads();
        float m =(sm.sRB[ii*2]  +sm.sRB[ii*2+1]) *(1.f/128.f);
        float ms=(sm.sRB[4+ii*2]+sm.sRB[5+ii*2])*(1.f/128.f);
        float rstd=rsqrtf(fmaxf(ms-m*m,0.f)+1e-8f);
        float y1=(f-m)*rstd*a.ln1g[128+cc]+a.ln1b[128+cc];
        a.qin1[(size_t)rr*128+cc]=y1;
        ((us16*)sm.sXb)[ii*128+cc]=f2us(y1);
        __syncthreads();
        float accq=gemv128(a.wsP+(size_t)2*8192, sm.sXb+ii*64, cc)+a.bq[128+cc];
        a.Qb1[(size_t)rr*128+cc]=f2us(accq);
        float acck=gemv128(a.wsP+(size_t)3*8192, sm.sYb+ii*64, cc)+a.bk[128+cc]+a.posK[qown*128+cc];
        a.Kb1[(size_t)rr*128+cc]=f2us(acck);
        float accv=gemv128(a.wsP+(size_t)4*8192, sm.sYb+ii*64, cc)+a.bv[128+cc]+a.posV[qown*128+cc];
        ((us16*)a.Vb1)[((size_t)rr>>1)*256+2*cc+(rr&1)]=f2us(accv);   // pair-major
    } else {
        // LNf (single barrier) + logits
        float s=f, s2=f*f;
        #pragma unroll
        for(int o=32;o;o>>=1){ s+=__shfl_xor(s,o,64); s2+=__shfl_xor(s2,o,64); }
        if((tid&63)==0){ sm.sRB[ii*2+((tid>>6)&1)]=s; sm.sRB[4+ii*2+((tid>>6)&1)]=s2; }
        __syncthreads();
        float m =(sm.sRB[ii*2]  +sm.sRB[ii*2+1]) *(1.f/128.f);
        float ms=(sm.sRB[4+ii*2]+sm.sRB[5+ii*2])*(1.f/128.f);
        float rstd=rsqrtf(fmaxf(ms-m*m,0.f)+1e-8f);
        sm.sX[ii*128+cc]=(f-m)*rstd*a.lnfg[cc]+a.lnfb[cc];
        __syncthreads();
        int w=tid>>6, lane=tid&63;
        int rowi=w>>1, neg=w&1;
        int rg = rowi? r2:r1;
        int id = neg? a.neg_seqs[rg] : a.pos_seqs[rg];
        const float* e=a.item_emb+(size_t)id*128;
        float s2l = sm.sX[rowi*128+lane]*e[lane] + sm.sX[rowi*128+lane+64]*e[lane+64];
        #pragma unroll
        for(int o=32;o;o>>=1) s2l+=__shfl_xor(s2l,o,64);
        if(lane==0) a.out[neg*ROWS+rg]=s2l;
    }
}

extern "C" void kernel_launch(void* const* d_in, const int* in_sizes, int n_in,
                              void* d_out, int out_size, void* d_ws, size_t ws_size,
                              hipStream_t stream) {
    KArgs a;
    a.log_seqs=(const int*)d_in[1];
    a.tmat    =(const int*)d_in[2];
    a.pos_seqs=(const int*)d_in[3];
    a.neg_seqs=(const int*)d_in[4];
    a.item_emb=(const float*)d_in[5];
    a.posK =(const float*)d_in[6];
    a.posV =(const float*)d_in[7];
    a.timeK=(const float*)d_in[8];
    a.timeV=(const float*)d_in[9];
    a.ln1g=(const float*)d_in[10];
    a.ln1b=(const float*)d_in[11];
    a.Wq=(const float*)d_in[12];
    a.bq=(const float*)d_in[13];
    a.Wk=(const float*)d_in[14];
    a.bk=(const float*)d_in[15];
    a.Wv=(const float*)d_in[16];
    a.bv=(const float*)d_in[17];
    a.ln2g=(const float*)d_in[18];
    a.ln2b=(const float*)d_in[19];
    a.W1=(const float*)d_in[20];
    a.b1=(const float*)d_in[21];
    a.W2=(const float*)d_in[22];
    a.b2=(const float*)d_in[23];
    a.lnfg=(const float*)d_in[24];
    a.lnfb=(const float*)d_in[25];

    const size_t MB=1u<<20;
    char* w=(char*)d_ws;
    a.qin0=(float*)(w+0*MB);
    a.qin1=(float*)(w+1*MB);
    a.Qb0 =(us16*) (w+2*MB);
    a.Kb0 =(us16*) (w+2*MB+512*1024);
    a.Vb0 =(us16*) (w+3*MB);
    a.Qb1 =(us16*) (w+3*MB+512*1024);
    a.Kb1 =(us16*) (w+4*MB);
    a.Vb1 =(us16*) (w+4*MB+512*1024);
    a.wsP =(unsigned*)(w+5*MB);           // 7 x 32KB row-pair-major bf16
    a.tmK =(us16*) (w+5*MB+256*1024);
    a.tmV =(us16*) (w+5*MB+384*1024);
    a.out =(float*)d_out;

    k_pre<<<946,256,0,stream>>>(a);
    k_blk<<<1024,256,0,stream>>>(a,0);
    k_blk<<<1024,256,0,stream>>>(a,1);
}